// Round 3
// baseline (550.428 us; speedup 1.0000x reference)
//
#include <hip/hip_runtime.h>
#include <stdint.h>

#define NB 64
#define NO 32
#define NI 512
#define ND 64

typedef __attribute__((ext_vector_type(8))) short short8;
typedef __attribute__((ext_vector_type(4))) float f32x4;

__device__ __forceinline__ float blo(unsigned int u) {
    union { unsigned int i; float f; } v; v.i = u << 16; return v.f;
}
__device__ __forceinline__ float bhi(unsigned int u) {
    union { unsigned int i; float f; } v; v.i = u & 0xFFFF0000u; return v.f;
}
__device__ __forceinline__ unsigned short f2bf(float f) {
    union { float f; unsigned int i; } v; v.f = f;
    return (unsigned short)((v.i + 0x7FFFu + ((v.i >> 16) & 1u)) >> 16);
}
__device__ __forceinline__ short8 pack8(const float4 a, const float4 b) {
    short8 r;
    r[0] = (short)f2bf(a.x); r[1] = (short)f2bf(a.y);
    r[2] = (short)f2bf(a.z); r[3] = (short)f2bf(a.w);
    r[4] = (short)f2bf(b.x); r[5] = (short)f2bf(b.y);
    r[6] = (short)f2bf(b.z); r[7] = (short)f2bf(b.w);
    return r;
}

// K1: x_hat[b,o,i,d] = sum_m W[o,i,d,m] * x[b,i,m]  (x, W fp32; xh stored bf16
// as xh[o][b][i][d]). Block: one o, 8 consecutive i. 4 waves; wave wv owns
// b-rows [16wv,16wv+16). MFMA 16x16x32 bf16: A[m=lane&15][k=quad*8+j],
// B[k=quad*8+j][n=lane&15], C: col=lane&15, row=quad*4+reg.
__global__ __launch_bounds__(256) void k_gemm(const float* __restrict__ x,
                                              const float* __restrict__ w,
                                              unsigned short* __restrict__ xh) {
    const int o  = blockIdx.x & 31;
    const int ig = blockIdx.x >> 5;          // i base = ig*8
    const int t  = threadIdx.x;
    const int wv = t >> 6;                   // b-tile
    const int l  = t & 63;
    const int q  = l >> 4;
    const int c  = l & 15;

    for (int ii = 0; ii < 8; ++ii) {
        const int i = ig * 8 + ii;
        // A frags: x[b = 16*wv + c][i][m = q*8 (+32)], fp32 -> bf16
        const float* ap = x + ((size_t)(16 * wv + c) * NI + i) * 64 + q * 8;
        const short8 a0 = pack8(*(const float4*)ap,        *(const float4*)(ap + 4));
        const short8 a1 = pack8(*(const float4*)(ap + 32), *(const float4*)(ap + 36));
        const size_t wbase = ((size_t)o * NI + i) * 64 * 64;
        f32x4 acc[4];
        #pragma unroll
        for (int td = 0; td < 4; ++td) {
            // B frags: W[o][i][d = 16*td + c][m = q*8 (+32)], fp32 -> bf16
            const float* bp = w + wbase + (size_t)(16 * td + c) * 64 + q * 8;
            const short8 b0 = pack8(*(const float4*)bp,        *(const float4*)(bp + 4));
            const short8 b1 = pack8(*(const float4*)(bp + 32), *(const float4*)(bp + 36));
            f32x4 z = {0.f, 0.f, 0.f, 0.f};
            z = __builtin_amdgcn_mfma_f32_16x16x32_bf16(a0, b0, z, 0, 0, 0);
            z = __builtin_amdgcn_mfma_f32_16x16x32_bf16(a1, b1, z, 0, 0, 0);
            acc[td] = z;
        }
        // store C[b=16wv+4q+r][d=16td+c] -> xh[o][b][i][d]
        #pragma unroll
        for (int td = 0; td < 4; ++td) {
            const int d = 16 * td + c;
            #pragma unroll
            for (int r = 0; r < 4; ++r) {
                const int b = 16 * wv + 4 * q + r;
                xh[(((size_t)o * NB + b) * NI + i) * ND + d] = f2bf(acc[td][r]);
            }
        }
    }
}

// Routing step. Block = (b,o). STEP: 0 (c=1/32, write b1), 1 (softmax(b1), write b2),
// 2 (softmax(b2), write final output fp32).
template<int STEP>
__global__ __launch_bounds__(256) void k_route(const unsigned short* __restrict__ xh,
                                               const float* __restrict__ b_in,
                                               float* __restrict__ b_out,
                                               float* __restrict__ outp) {
    constexpr int XS = 68;                         // padded LDS row stride (bf16 elems)
    extern __shared__ char smem[];
    unsigned short* xh_s = (unsigned short*)smem;  // 512*68*2 = 69632 B
    float* c_s = (float*)(smem + 69632);           // 512*4   = 2048 B
    float* P   = (float*)(smem + 69632 + 2048);    // 4*64*4  = 1024 B
    float* o_s = (float*)(smem + 69632 + 2048 + 1024); // 64*4 = 256 B  (total 72960)

    const int t = threadIdx.x;
    const int b = blockIdx.x >> 5;
    const int o = blockIdx.x & 31;

    float b_own0 = 0.f, b_own1 = 0.f;
    if (STEP > 0) {
        const float* bp = b_in + (size_t)b * (NO * NI);
        #pragma unroll
        for (int s = 0; s < 2; ++s) {
            const int i = t + s * 256;
            float v[NO];
            #pragma unroll
            for (int oo = 0; oo < NO; ++oo) v[oo] = bp[(size_t)oo * NI + i];
            float m = v[0];
            #pragma unroll
            for (int oo = 1; oo < NO; ++oo) m = fmaxf(m, v[oo]);
            float Z = 0.f;
            #pragma unroll
            for (int oo = 0; oo < NO; ++oo) Z += __expf(v[oo] - m);
            const float own = bp[(size_t)o * NI + i];   // L2 hit; avoids dynamic index
            c_s[i] = __expf(own - m) / Z;
            if (s == 0) b_own0 = own; else b_own1 = own;
        }
        __syncthreads();
    }

    // Stage xh[o][b] tile into LDS; fused c-weighted accumulation of s[d].
    const int dg = t & 7;                 // d-chunk (8 d's)
    const int ip = t >> 3;                // i within 32-group
    const unsigned short* gsrc = xh + ((size_t)o * NB + b) * NI * ND;
    float acc[8] = {0, 0, 0, 0, 0, 0, 0, 0};
    #pragma unroll
    for (int k = 0; k < 16; ++k) {
        const int i = 32 * k + ip;
        const uint4 raw = *(const uint4*)(gsrc + (size_t)i * ND + dg * 8);
        unsigned short* dst = xh_s + i * XS + dg * 8;
        *(uint2*)dst = make_uint2(raw.x, raw.y);
        *(uint2*)(dst + 4) = make_uint2(raw.z, raw.w);
        const float cw = (STEP == 0) ? 0.03125f : c_s[i];
        acc[0] += cw * blo(raw.x); acc[1] += cw * bhi(raw.x);
        acc[2] += cw * blo(raw.y); acc[3] += cw * bhi(raw.y);
        acc[4] += cw * blo(raw.z); acc[5] += cw * bhi(raw.z);
        acc[6] += cw * blo(raw.w); acc[7] += cw * bhi(raw.w);
    }
    // Reduce over the 8 ip-subgroups within each wave (lane bits 3..5).
    #pragma unroll
    for (int j = 0; j < 8; ++j) {
        acc[j] += __shfl_xor(acc[j], 8);
        acc[j] += __shfl_xor(acc[j], 16);
        acc[j] += __shfl_xor(acc[j], 32);
    }
    const int lane = t & 63;
    const int wv = t >> 6;
    if (lane < 8) {
        #pragma unroll
        for (int j = 0; j < 8; ++j) P[wv * 64 + lane * 8 + j] = acc[j];
    }
    __syncthreads();

    // Wave 0: finish s[d], squash, emit out vector.
    if (t < 64) {
        const float sv = P[t] + P[64 + t] + P[128 + t] + P[192 + t];
        float s2 = sv * sv;
        #pragma unroll
        for (int m = 1; m < 64; m <<= 1) s2 += __shfl_xor(s2, m);
        const float n = sqrtf(s2);
        const float sc = (s2 / (1.0f + s2)) / (n + 1e-8f);
        const float ov = sv * sc;
        o_s[t] = ov;
        if (STEP == 2) outp[((size_t)b * NO + o) * ND + t] = ov;   // fp32 output
    }
    __syncthreads();

    // b-update: b_out[b,o,i] = b_own + sum_d xh[i][d]*out[d]
    if (STEP < 2) {
        #pragma unroll
        for (int s = 0; s < 2; ++s) {
            const int i = t + s * 256;
            const unsigned short* row = xh_s + i * XS;
            float dot = 0.f;
            #pragma unroll
            for (int cc = 0; cc < 8; ++cc) {
                const uint2 ra = *(const uint2*)(row + cc * 8);
                const uint2 rb = *(const uint2*)(row + cc * 8 + 4);
                const float* oc = o_s + cc * 8;
                dot += blo(ra.x) * oc[0] + bhi(ra.x) * oc[1]
                     + blo(ra.y) * oc[2] + bhi(ra.y) * oc[3]
                     + blo(rb.x) * oc[4] + bhi(rb.x) * oc[5]
                     + blo(rb.y) * oc[6] + bhi(rb.y) * oc[7];
            }
            b_out[((size_t)b * NO + o) * NI + i] = (s == 0 ? b_own0 : b_own1) + dot;
        }
    }
}

extern "C" void kernel_launch(void* const* d_in, const int* in_sizes, int n_in,
                              void* d_out, int out_size, void* d_ws, size_t ws_size,
                              hipStream_t stream) {
    const float* x = (const float*)d_in[0];        // [64,512,64] fp32
    const float* w = (const float*)d_in[1];        // [32,512,64,64] fp32
    float* outp = (float*)d_out;                   // [64,32,64] fp32

    char* ws = (char*)d_ws;
    unsigned short* xh = (unsigned short*)ws;                  // 128 MiB, xh[o][b][i][d] bf16
    float* ba = (float*)(ws + (size_t)134217728);              // 4 MiB logits buf A
    float* bb = (float*)(ws + (size_t)134217728 + 4194304);    // 4 MiB logits buf B

    const int smem = 69632 + 2048 + 1024 + 256;                // 72960 B
    hipFuncSetAttribute(reinterpret_cast<const void*>(&k_route<0>),
                        hipFuncAttributeMaxDynamicSharedMemorySize, smem);
    hipFuncSetAttribute(reinterpret_cast<const void*>(&k_route<1>),
                        hipFuncAttributeMaxDynamicSharedMemorySize, smem);
    hipFuncSetAttribute(reinterpret_cast<const void*>(&k_route<2>),
                        hipFuncAttributeMaxDynamicSharedMemorySize, smem);

    k_gemm<<<dim3(2048), dim3(256), 0, stream>>>(x, w, xh);
    k_route<0><<<dim3(2048), dim3(256), smem, stream>>>(xh, nullptr, ba, nullptr);
    k_route<1><<<dim3(2048), dim3(256), smem, stream>>>(xh, ba, bb, nullptr);
    k_route<2><<<dim3(2048), dim3(256), smem, stream>>>(xh, bb, nullptr, outp);
}

// Round 4
// 530.457 us; speedup vs baseline: 1.0376x; 1.0376x over previous
//
#include <hip/hip_runtime.h>
#include <stdint.h>

#define NB 64
#define NO 32
#define NI 512
#define ND 64

typedef __attribute__((ext_vector_type(8))) short short8;
typedef __attribute__((ext_vector_type(4))) float f32x4;

__device__ __forceinline__ float blo(unsigned int u) {
    union { unsigned int i; float f; } v; v.i = u << 16; return v.f;
}
__device__ __forceinline__ float bhi(unsigned int u) {
    union { unsigned int i; float f; } v; v.i = u & 0xFFFF0000u; return v.f;
}
__device__ __forceinline__ unsigned short f2bf(float f) {
    union { float f; unsigned int i; } v; v.f = f;
    return (unsigned short)((v.i + 0x7FFFu + ((v.i >> 16) & 1u)) >> 16);
}
__device__ __forceinline__ short8 pack8(const float4 a, const float4 b) {
    short8 r;
    r[0] = (short)f2bf(a.x); r[1] = (short)f2bf(a.y);
    r[2] = (short)f2bf(a.z); r[3] = (short)f2bf(a.w);
    r[4] = (short)f2bf(b.x); r[5] = (short)f2bf(b.y);
    r[6] = (short)f2bf(b.z); r[7] = (short)f2bf(b.w);
    return r;
}

__device__ __forceinline__ void ld_a(float4 r[4], const float* __restrict__ p) {
    r[0] = *(const float4*)(p);
    r[1] = *(const float4*)(p + 4);
    r[2] = *(const float4*)(p + 32);
    r[3] = *(const float4*)(p + 36);
}
__device__ __forceinline__ void ld_b(float4 r[16], const float* __restrict__ p) {
    #pragma unroll
    for (int td = 0; td < 4; ++td) {
        r[4 * td + 0] = *(const float4*)(p + td * 1024);
        r[4 * td + 1] = *(const float4*)(p + td * 1024 + 4);
        r[4 * td + 2] = *(const float4*)(p + td * 1024 + 32);
        r[4 * td + 3] = *(const float4*)(p + td * 1024 + 36);
    }
}

// K1: x_hat[b,o,i,d] = sum_m W[o,i,d,m] * x[b,i,m]  (x, W fp32; xh bf16 as
// xh[o][b][i][d]). Block: one o, 8 i. 4 waves by b-tile. Software-pipelined:
// raw fp32 loads for ii+1 issued before pack/MFMA of ii (latency was the
// round-3 bottleneck: 60 VGPR, 1.56 TB/s, nothing busy).
__global__ __launch_bounds__(256) void k_gemm(const float* __restrict__ x,
                                              const float* __restrict__ w,
                                              unsigned short* __restrict__ xh) {
    const int o  = blockIdx.x & 31;
    const int ig = blockIdx.x >> 5;
    const int t  = threadIdx.x;
    const int wv = t >> 6;
    const int l  = t & 63;
    const int q  = l >> 4;
    const int c  = l & 15;

    const float* ap0 = x + ((size_t)(16 * wv + c) * NI + ig * 8) * 64 + q * 8;
    const float* bp0 = w + ((size_t)o * NI + ig * 8) * 4096 + (size_t)c * 64 + q * 8;

    float4 ra[4], rb[16], na[4], nb[16];
    ld_a(ra, ap0);
    ld_b(rb, bp0);

    #pragma unroll
    for (int ii = 0; ii < 8; ++ii) {
        if (ii < 7) {                       // prefetch next iteration's raw data
            ld_a(na, ap0 + (ii + 1) * 64);
            ld_b(nb, bp0 + (size_t)(ii + 1) * 4096);
        }
        const int i = ig * 8 + ii;
        const short8 a0 = pack8(ra[0], ra[1]);
        const short8 a1 = pack8(ra[2], ra[3]);
        f32x4 acc[4];
        #pragma unroll
        for (int td = 0; td < 4; ++td) {
            const short8 b0 = pack8(rb[4 * td + 0], rb[4 * td + 1]);
            const short8 b1 = pack8(rb[4 * td + 2], rb[4 * td + 3]);
            f32x4 z = {0.f, 0.f, 0.f, 0.f};
            z = __builtin_amdgcn_mfma_f32_16x16x32_bf16(a0, b0, z, 0, 0, 0);
            z = __builtin_amdgcn_mfma_f32_16x16x32_bf16(a1, b1, z, 0, 0, 0);
            acc[td] = z;
        }
        // store C[b=16wv+4q+r][d=16td+c] -> xh[o][b][i][d]   (verified layout)
        #pragma unroll
        for (int td = 0; td < 4; ++td) {
            const int d = 16 * td + c;
            #pragma unroll
            for (int r = 0; r < 4; ++r) {
                const int b = 16 * wv + 4 * q + r;
                xh[(((size_t)o * NB + b) * NI + i) * ND + d] = f2bf(acc[td][r]);
            }
        }
        #pragma unroll
        for (int j = 0; j < 4; ++j)  ra[j] = na[j];
        #pragma unroll
        for (int j = 0; j < 16; ++j) rb[j] = nb[j];
    }
}

// Routing step. Block = (b,o). STEP: 0 (c=1/32, write b1), 1 (softmax(b1),
// write b2), 2 (softmax(b2), write final fp32 output).
// xh tile held in REGISTERS (16 x uint4/thread), loads issued before softmax
// so their latency overlaps it. LDS is only c_s/P/o_s (3.3 KB) -> ~4 blocks/CU
// (round-3 version: 73 KB LDS, 2 blocks/CU, 115 us each).
template<int STEP>
__global__ __launch_bounds__(256) void k_route(const unsigned short* __restrict__ xh,
                                               const float* __restrict__ b_in,
                                               float* __restrict__ b_out,
                                               float* __restrict__ outp) {
    __shared__ float c_s[NI];      // 2048 B
    __shared__ float P[4 * 64];    // 1024 B
    __shared__ float o_s[64];      // 256 B

    const int t  = threadIdx.x;
    const int b  = blockIdx.x >> 5;
    const int o  = blockIdx.x & 31;
    const int dg = t & 7;          // d-chunk (8 d's)
    const int ip = t >> 3;         // i mod 32

    // Issue all xh loads first; thread (ip,dg) holds rows i=32k+ip, d=8dg..8dg+7.
    const unsigned short* gsrc = xh + ((size_t)o * NB + b) * NI * ND;
    uint4 raw[16];
    #pragma unroll
    for (int k = 0; k < 16; ++k)
        raw[k] = *(const uint4*)(gsrc + (size_t)(32 * k + ip) * ND + dg * 8);

    // Softmax over o (online, no register array) while loads are in flight.
    const float* bp = (STEP > 0) ? (b_in + (size_t)b * (NO * NI)) : nullptr;
    if (STEP > 0) {
        #pragma unroll
        for (int s = 0; s < 2; ++s) {
            const int i = t + s * 256;
            float m = -INFINITY, Z = 0.f;
            #pragma unroll
            for (int oo = 0; oo < NO; ++oo) {
                const float v = bp[(size_t)oo * NI + i];
                const float nm = fmaxf(m, v);
                Z = Z * __expf(m - nm) + __expf(v - nm);
                m = nm;
            }
            c_s[i] = __expf(bp[(size_t)o * NI + i] - m) / Z;
        }
        __syncthreads();
    }

    // c-weighted accumulation of s[d] from registers.
    float acc[8] = {0, 0, 0, 0, 0, 0, 0, 0};
    #pragma unroll
    for (int k = 0; k < 16; ++k) {
        const float cw = (STEP == 0) ? 0.03125f : c_s[32 * k + ip];
        acc[0] += cw * blo(raw[k].x); acc[1] += cw * bhi(raw[k].x);
        acc[2] += cw * blo(raw[k].y); acc[3] += cw * bhi(raw[k].y);
        acc[4] += cw * blo(raw[k].z); acc[5] += cw * bhi(raw[k].z);
        acc[6] += cw * blo(raw[k].w); acc[7] += cw * bhi(raw[k].w);
    }
    #pragma unroll
    for (int j = 0; j < 8; ++j) {      // reduce over ip within wave (lane bits 3..5)
        acc[j] += __shfl_xor(acc[j], 8);
        acc[j] += __shfl_xor(acc[j], 16);
        acc[j] += __shfl_xor(acc[j], 32);
    }
    const int lane = t & 63;
    const int wv = t >> 6;
    if (lane < 8) {
        #pragma unroll
        for (int j = 0; j < 8; ++j) P[wv * 64 + lane * 8 + j] = acc[j];
    }
    __syncthreads();

    // Wave 0: finish s[d], squash, emit out vector.
    if (t < 64) {
        const float sv = P[t] + P[64 + t] + P[128 + t] + P[192 + t];
        float s2 = sv * sv;
        #pragma unroll
        for (int m = 1; m < 64; m <<= 1) s2 += __shfl_xor(s2, m);
        const float n = sqrtf(s2);
        const float sc = (s2 / (1.0f + s2)) / (n + 1e-8f);
        const float ov = sv * sc;
        o_s[t] = ov;
        if (STEP == 2) outp[((size_t)b * NO + o) * ND + t] = ov;
    }
    __syncthreads();

    // b-update from registers: dot per row, reduce across dg (lane bits 0..2).
    if (STEP < 2) {
        float oc[8];
        #pragma unroll
        for (int j = 0; j < 8; ++j) oc[j] = o_s[dg * 8 + j];
        float w1 = 0.f, w2 = 0.f;
        #pragma unroll
        for (int k = 0; k < 16; ++k) {
            float pd = blo(raw[k].x) * oc[0] + bhi(raw[k].x) * oc[1]
                     + blo(raw[k].y) * oc[2] + bhi(raw[k].y) * oc[3]
                     + blo(raw[k].z) * oc[4] + bhi(raw[k].z) * oc[5]
                     + blo(raw[k].w) * oc[6] + bhi(raw[k].w) * oc[7];
            pd += __shfl_xor(pd, 1);
            pd += __shfl_xor(pd, 2);
            pd += __shfl_xor(pd, 4);   // all 8 lanes of the group now hold dot(i=32k+ip)
            if (k == dg)     w1 = pd;  // compile-time k vs lane dg -> cndmask, no spill
            if (k == dg + 8) w2 = pd;
        }
        const int i1 = 32 * dg + ip;
        const int i2 = 32 * (dg + 8) + ip;
        float* bo = b_out + ((size_t)b * NO + o) * NI;
        const float own1 = (STEP == 0) ? 0.f : bp[(size_t)o * NI + i1];
        const float own2 = (STEP == 0) ? 0.f : bp[(size_t)o * NI + i2];
        bo[i1] = own1 + w1;
        bo[i2] = own2 + w2;
    }
}

extern "C" void kernel_launch(void* const* d_in, const int* in_sizes, int n_in,
                              void* d_out, int out_size, void* d_ws, size_t ws_size,
                              hipStream_t stream) {
    const float* x = (const float*)d_in[0];        // [64,512,64] fp32
    const float* w = (const float*)d_in[1];        // [32,512,64,64] fp32
    float* outp = (float*)d_out;                   // [64,32,64] fp32

    char* ws = (char*)d_ws;
    unsigned short* xh = (unsigned short*)ws;                  // 128 MiB, xh[o][b][i][d] bf16
    float* ba = (float*)(ws + (size_t)134217728);              // 4 MiB logits buf A
    float* bb = (float*)(ws + (size_t)134217728 + 4194304);    // 4 MiB logits buf B

    k_gemm<<<dim3(2048), dim3(256), 0, stream>>>(x, w, xh);
    k_route<0><<<dim3(2048), dim3(256), 0, stream>>>(xh, nullptr, ba, nullptr);
    k_route<1><<<dim3(2048), dim3(256), 0, stream>>>(xh, ba, bb, nullptr);
    k_route<2><<<dim3(2048), dim3(256), 0, stream>>>(xh, bb, nullptr, outp);
}

// Round 5
// 487.049 us; speedup vs baseline: 1.1301x; 1.0891x over previous
//
#include <hip/hip_runtime.h>
#include <stdint.h>

#define NB 64
#define NO 32
#define NI 512
#define ND 64

typedef __attribute__((ext_vector_type(8))) short short8;
typedef __attribute__((ext_vector_type(4))) float f32x4;

// async global->LDS DMA, 16 B/lane. Global addr per-lane; LDS base wave-uniform,
// lane i lands at base + 16*i (m104/m108 semantics).
#define GL2LDS(g, s) __builtin_amdgcn_global_load_lds( \
    (const __attribute__((address_space(1))) void*)(g), \
    (__attribute__((address_space(3))) void*)(s), 16, 0, 0)

__device__ __forceinline__ float blo(unsigned int u) {
    union { unsigned int i; float f; } v; v.i = u << 16; return v.f;
}
__device__ __forceinline__ float bhi(unsigned int u) {
    union { unsigned int i; float f; } v; v.i = u & 0xFFFF0000u; return v.f;
}
__device__ __forceinline__ unsigned short f2bf(float f) {
    union { float f; unsigned int i; } v; v.f = f;
    return (unsigned short)((v.i + 0x7FFFu + ((v.i >> 16) & 1u)) >> 16);
}
__device__ __forceinline__ short8 pack8(const float4 a, const float4 b) {
    short8 r;
    r[0] = (short)f2bf(a.x); r[1] = (short)f2bf(a.y);
    r[2] = (short)f2bf(a.z); r[3] = (short)f2bf(a.w);
    r[4] = (short)f2bf(b.x); r[5] = (short)f2bf(b.y);
    r[6] = (short)f2bf(b.z); r[7] = (short)f2bf(b.w);
    return r;
}
__device__ __forceinline__ void ld_a(float4 r[4], const float* __restrict__ p) {
    r[0] = *(const float4*)(p);
    r[1] = *(const float4*)(p + 4);
    r[2] = *(const float4*)(p + 32);
    r[3] = *(const float4*)(p + 36);
}

// K1: x_hat[b,o,i,d] = sum_m W[o,i,d,m] x[b,i,m]; xh bf16 as xh[o][b][i][d].
// Block (o, ig): 8 i's, 4 waves by b-tile. W staged by global_load_lds into a
// triple-buffered LDS tile with XOR-swizzled 16-B granules:
//   LDS slot(r,g) = r*16 + (g ^ (r&15))   (r = d-row 0..63, g = col-granule 0..15)
// so fragment ds_read_b128s are bank-uniform (8 words/bank). x via register
// prefetch (L2-hot, small). In-flight/CU = blocks*2 stages*16KB >> 9.2 KB needed.
__global__ __launch_bounds__(256) void k_gemm(const float* __restrict__ x,
                                              const float* __restrict__ w,
                                              unsigned short* __restrict__ xh) {
    __shared__ float Wl[3][4096];            // 48 KB
    const int o  = blockIdx.x & 31;
    const int ig = blockIdx.x >> 5;
    const int t  = threadIdx.x;
    const int wv = t >> 6;
    const int l  = t & 63;
    const int q  = l >> 4;
    const int c  = l & 15;

    const float* wbase = w + ((size_t)o * NI + ig * 8) * 4096;

    // stage W[o][ig*8+ii] (16 KB) into Wl[buf], swizzled
    auto stage = [&](int buf, int ii) {
        const float* src = wbase + (size_t)ii * 4096;
        #pragma unroll
        for (int k = 0; k < 4; ++k) {
            const int s = wv * 256 + k * 64 + l;         // LDS slot this lane fills
            const int r = s >> 4;
            const int g = (s & 15) ^ (r & 15);           // inverse of slot swizzle
            GL2LDS(src + r * 64 + g * 4, &Wl[buf][(wv * 256 + k * 64) * 4]);
        }
    };

    const float* ap0 = x + ((size_t)(16 * wv + c) * NI + ig * 8) * 64 + q * 8;
    float4 ra[4], na[4];
    ld_a(ra, ap0);
    stage(0, 0);
    stage(1, 1);

    #pragma unroll
    for (int ii = 0; ii < 8; ++ii) {
        __syncthreads();                     // drains vmcnt -> stage(ii) visible
        if (ii < 6) stage((ii + 2) % 3, ii + 2);
        if (ii < 7) ld_a(na, ap0 + (ii + 1) * 64);

        const int i = ig * 8 + ii;
        const float* Wb = Wl[ii % 3];
        const short8 a0 = pack8(ra[0], ra[1]);
        const short8 a1 = pack8(ra[2], ra[3]);
        f32x4 acc[4];
        #pragma unroll
        for (int td = 0; td < 4; ++td) {
            const int r = 16 * td + c;                   // r & 15 == c
            const float4 f0 = *(const float4*)&Wb[(r * 16 + ((2 * q)     ^ c)) * 4];
            const float4 f1 = *(const float4*)&Wb[(r * 16 + ((2 * q + 1) ^ c)) * 4];
            const float4 f2 = *(const float4*)&Wb[(r * 16 + ((2 * q + 8) ^ c)) * 4];
            const float4 f3 = *(const float4*)&Wb[(r * 16 + ((2 * q + 9) ^ c)) * 4];
            const short8 b0 = pack8(f0, f1);             // cols q*8 .. q*8+7
            const short8 b1 = pack8(f2, f3);             // cols q*8+32 .. +39
            f32x4 z = {0.f, 0.f, 0.f, 0.f};
            z = __builtin_amdgcn_mfma_f32_16x16x32_bf16(a0, b0, z, 0, 0, 0);
            z = __builtin_amdgcn_mfma_f32_16x16x32_bf16(a1, b1, z, 0, 0, 0);
            acc[td] = z;
        }
        // store C[b=16wv+4q+r][d=16td+c] -> xh[o][b][i][d]   (verified layout)
        #pragma unroll
        for (int td = 0; td < 4; ++td) {
            const int d = 16 * td + c;
            #pragma unroll
            for (int rr = 0; rr < 4; ++rr) {
                const int b = 16 * wv + 4 * q + rr;
                xh[(((size_t)o * NB + b) * NI + i) * ND + d] = f2bf(acc[td][rr]);
            }
        }
        #pragma unroll
        for (int j = 0; j < 4; ++j) ra[j] = na[j];
    }
}

// Softmax stats per (b,i): m = max_o logits, and 1/Z. 128 blocks.
__global__ __launch_bounds__(256) void k_soft(const float* __restrict__ b_in,
                                              float* __restrict__ mz) {
    const int p = blockIdx.x * 256 + threadIdx.x;        // p = b*512 + i
    const int b = p >> 9, i = p & 511;
    const float* bp = b_in + (size_t)b * NO * NI + i;
    float v[NO];
    #pragma unroll
    for (int oo = 0; oo < NO; ++oo) v[oo] = bp[(size_t)oo * NI];
    float m = v[0];
    #pragma unroll
    for (int oo = 1; oo < NO; ++oo) m = fmaxf(m, v[oo]);
    float Z = 0.f;
    #pragma unroll
    for (int oo = 0; oo < NO; ++oo) Z += __expf(v[oo] - m);
    mz[p] = m;
    mz[NB * NI + p] = 1.0f / Z;
}

// Routing step. Block = (b,o). xh tile (64 KB) staged via global_load_lds
// (64 KB in flight per block -> BW-bound, not latency-bound). Softmax weights
// from precomputed m,1/Z (k_soft) - 2 exp/thread instead of 64.
template<int STEP>
__global__ __launch_bounds__(256) void k_route(const unsigned short* __restrict__ xh,
                                               const float* __restrict__ b_in,
                                               const float* __restrict__ mz,
                                               float* __restrict__ b_out,
                                               float* __restrict__ outp) {
    extern __shared__ char smem[];
    unsigned short* tile = (unsigned short*)smem;        // 65536 B, rows i*128B
    __shared__ float c_s[NI];
    __shared__ float P[4 * 64];
    __shared__ float o_s[64];

    const int t  = threadIdx.x;
    const int b  = blockIdx.x >> 5;
    const int o  = blockIdx.x & 31;
    const int wv = t >> 6;
    const int l  = t & 63;
    const int dg = t & 7;
    const int ip = t >> 3;

    // DMA the whole 64-KB xh[o][b] tile: wave wv covers 16 KB as 16 x 1-KB instrs.
    const unsigned short* gsrc = xh + ((size_t)o * NB + b) * NI * ND;
    #pragma unroll
    for (int k = 0; k < 16; ++k) {
        GL2LDS(gsrc + wv * 8192 + k * 512 + l * 8, tile + wv * 8192 + k * 512);
    }

    const float* bp = (STEP > 0) ? (b_in + ((size_t)b * NO + o) * NI) : nullptr;
    if (STEP > 0) {
        const float* mrow = mz + (size_t)b * NI;
        const float* zrow = mz + (size_t)(NB * NI) + (size_t)b * NI;
        #pragma unroll
        for (int s = 0; s < 2; ++s) {
            const int i = t + s * 256;
            c_s[i] = __expf(bp[i] - mrow[i]) * zrow[i];  // zrow holds 1/Z
        }
    }
    __syncthreads();                                     // drains DMA + c_s

    // c-weighted accumulation of s[d] from LDS (rows 128 B -> bank-even b128s).
    float acc[8] = {0, 0, 0, 0, 0, 0, 0, 0};
    #pragma unroll
    for (int k = 0; k < 16; ++k) {
        const int i = 32 * k + ip;
        const uint4 raw = *(const uint4*)(tile + i * ND + dg * 8);
        const float cw = (STEP == 0) ? 0.03125f : c_s[i];
        acc[0] += cw * blo(raw.x); acc[1] += cw * bhi(raw.x);
        acc[2] += cw * blo(raw.y); acc[3] += cw * bhi(raw.y);
        acc[4] += cw * blo(raw.z); acc[5] += cw * bhi(raw.z);
        acc[6] += cw * blo(raw.w); acc[7] += cw * bhi(raw.w);
    }
    #pragma unroll
    for (int j = 0; j < 8; ++j) {          // reduce over ip within wave (bits 3..5)
        acc[j] += __shfl_xor(acc[j], 8);
        acc[j] += __shfl_xor(acc[j], 16);
        acc[j] += __shfl_xor(acc[j], 32);
    }
    if (l < 8) {
        #pragma unroll
        for (int j = 0; j < 8; ++j) P[wv * 64 + l * 8 + j] = acc[j];
    }
    __syncthreads();

    // Wave 0: finish s[d], squash, emit out vector.
    if (t < 64) {
        const float sv = P[t] + P[64 + t] + P[128 + t] + P[192 + t];
        float s2 = sv * sv;
        #pragma unroll
        for (int m = 1; m < 64; m <<= 1) s2 += __shfl_xor(s2, m);
        const float n = sqrtf(s2);
        const float sc = (s2 / (1.0f + s2)) / (n + 1e-8f);
        const float ov = sv * sc;
        o_s[t] = ov;
        if (STEP == 2) outp[((size_t)b * NO + o) * ND + t] = ov;
    }
    __syncthreads();

    // b-update: dot per row from LDS, reduce across dg (bits 0..2).
    if (STEP < 2) {
        float oc[8];
        #pragma unroll
        for (int j = 0; j < 8; ++j) oc[j] = o_s[dg * 8 + j];
        float w1 = 0.f, w2 = 0.f;
        #pragma unroll
        for (int k = 0; k < 16; ++k) {
            const uint4 raw = *(const uint4*)(tile + (32 * k + ip) * ND + dg * 8);
            float pd = blo(raw.x) * oc[0] + bhi(raw.x) * oc[1]
                     + blo(raw.y) * oc[2] + bhi(raw.y) * oc[3]
                     + blo(raw.z) * oc[4] + bhi(raw.z) * oc[5]
                     + blo(raw.w) * oc[6] + bhi(raw.w) * oc[7];
            pd += __shfl_xor(pd, 1);
            pd += __shfl_xor(pd, 2);
            pd += __shfl_xor(pd, 4);
            if (k == dg)     w1 = pd;
            if (k == dg + 8) w2 = pd;
        }
        const int i1 = 32 * dg + ip;
        const int i2 = 32 * (dg + 8) + ip;
        float* bo = b_out + ((size_t)b * NO + o) * NI;
        bo[i1] = ((STEP == 0) ? 0.f : bp[i1]) + w1;
        bo[i2] = ((STEP == 0) ? 0.f : bp[i2]) + w2;
    }
}

extern "C" void kernel_launch(void* const* d_in, const int* in_sizes, int n_in,
                              void* d_out, int out_size, void* d_ws, size_t ws_size,
                              hipStream_t stream) {
    const float* x = (const float*)d_in[0];        // [64,512,64] fp32
    const float* w = (const float*)d_in[1];        // [32,512,64,64] fp32
    float* outp = (float*)d_out;                   // [64,32,64] fp32

    char* ws = (char*)d_ws;
    unsigned short* xh = (unsigned short*)ws;                       // 128 MiB bf16 xh[o][b][i][d]
    float* ba = (float*)(ws + (size_t)134217728);                   // 4 MiB logits A
    float* bb = (float*)(ws + (size_t)134217728 + 4194304);         // 4 MiB logits B
    float* mz = (float*)(ws + (size_t)134217728 + 2 * 4194304);     // 256 KiB m / 1/Z

    const int smem = 65536;
    hipFuncSetAttribute(reinterpret_cast<const void*>(&k_route<0>),
                        hipFuncAttributeMaxDynamicSharedMemorySize, smem);
    hipFuncSetAttribute(reinterpret_cast<const void*>(&k_route<1>),
                        hipFuncAttributeMaxDynamicSharedMemorySize, smem);
    hipFuncSetAttribute(reinterpret_cast<const void*>(&k_route<2>),
                        hipFuncAttributeMaxDynamicSharedMemorySize, smem);

    k_gemm<<<dim3(2048), dim3(256), 0, stream>>>(x, w, xh);
    k_route<0><<<dim3(2048), dim3(256), smem, stream>>>(xh, nullptr, nullptr, ba, nullptr);
    k_soft<<<dim3(128), dim3(256), 0, stream>>>(ba, mz);
    k_route<1><<<dim3(2048), dim3(256), smem, stream>>>(xh, ba, mz, bb, nullptr);
    k_soft<<<dim3(128), dim3(256), 0, stream>>>(bb, mz);
    k_route<2><<<dim3(2048), dim3(256), smem, stream>>>(xh, bb, mz, nullptr, outp);
}

// Round 6
// 466.078 us; speedup vs baseline: 1.1810x; 1.0450x over previous
//
#include <hip/hip_runtime.h>
#include <stdint.h>

#define NB 64
#define NO 32
#define NI 512
#define ND 64

typedef __attribute__((ext_vector_type(8))) short short8;
typedef __attribute__((ext_vector_type(4))) float f32x4;

// async global->LDS DMA, 16 B/lane. Global addr per-lane; LDS base wave-uniform,
// lane i lands at base + 16*i (m104/m108 semantics).
#define GL2LDS(g, s) __builtin_amdgcn_global_load_lds( \
    (const __attribute__((address_space(1))) void*)(g), \
    (__attribute__((address_space(3))) void*)(s), 16, 0, 0)

__device__ __forceinline__ float blo(unsigned int u) {
    union { unsigned int i; float f; } v; v.i = u << 16; return v.f;
}
__device__ __forceinline__ float bhi(unsigned int u) {
    union { unsigned int i; float f; } v; v.i = u & 0xFFFF0000u; return v.f;
}
__device__ __forceinline__ unsigned short f2bf(float f) {
    union { float f; unsigned int i; } v; v.f = f;
    return (unsigned short)((v.i + 0x7FFFu + ((v.i >> 16) & 1u)) >> 16);
}
__device__ __forceinline__ short8 pack8(const float4 a, const float4 b) {
    short8 r;
    r[0] = (short)f2bf(a.x); r[1] = (short)f2bf(a.y);
    r[2] = (short)f2bf(a.z); r[3] = (short)f2bf(a.w);
    r[4] = (short)f2bf(b.x); r[5] = (short)f2bf(b.y);
    r[6] = (short)f2bf(b.z); r[7] = (short)f2bf(b.w);
    return r;
}
__device__ __forceinline__ void ld_a(float4 r[4], const float* __restrict__ p) {
    r[0] = *(const float4*)(p);
    r[1] = *(const float4*)(p + 4);
    r[2] = *(const float4*)(p + 32);
    r[3] = *(const float4*)(p + 36);
}

// K1: x_hat = W x, stored bf16 in PERMUTED d-order: d' = 4c + td  (d = 16 td + c).
// All routing reductions over d are permutation-invariant; only the final output
// write remaps. This makes each lane's 4 C-values per b-row contiguous (uint2),
// turning 16 scattered 2B stores/iter into 4 coalesced 8B stores. Stores are
// deferred one iteration so the K-loop barrier's vmcnt(0) drain never waits on
// fresh stores (round-5 serializer).
__global__ __launch_bounds__(256) void k_gemm(const float* __restrict__ x,
                                              const float* __restrict__ w,
                                              unsigned short* __restrict__ xh) {
    __shared__ float Wl[3][4096];            // 48 KB, triple-buffered W tiles
    const int o  = blockIdx.x & 31;
    const int ig = blockIdx.x >> 5;
    const int t  = threadIdx.x;
    const int wv = t >> 6;
    const int l  = t & 63;
    const int q  = l >> 4;
    const int c  = l & 15;

    const float* wbase = w + ((size_t)o * NI + ig * 8) * 4096;

    // stage W[o][ig*8+ii] (16 KB) into Wl[buf], XOR-swizzled granules
    // (slot(r,g) = r*16 + (g ^ (r&15)); bank-uniform fragment reads).
    auto stage = [&](int buf, int ii) {
        const float* src = wbase + (size_t)ii * 4096;
        #pragma unroll
        for (int k = 0; k < 4; ++k) {
            const int s = wv * 256 + k * 64 + l;
            const int r = s >> 4;
            const int g = (s & 15) ^ (r & 15);
            GL2LDS(src + r * 64 + g * 4, &Wl[buf][(wv * 256 + k * 64) * 4]);
        }
    };

    const float* ap0 = x + ((size_t)(16 * wv + c) * NI + ig * 8) * 64 + q * 8;
    float4 ra[4], na[4];
    ld_a(ra, ap0);
    stage(0, 0);
    stage(1, 1);

    uint2 cst[4];
    #pragma unroll
    for (int ii = 0; ii < 8; ++ii) {
        __syncthreads();                     // stage(ii) visible; drains only iter-old vmcnt
        if (ii > 0) {                        // store iter ii-1's C (fresh stores AFTER barrier)
            #pragma unroll
            for (int rr = 0; rr < 4; ++rr) {
                const int bq = 16 * wv + 4 * q + rr;
                *(uint2*)(xh + (((size_t)o * NB + bq) * NI + (ig * 8 + ii - 1)) * ND + 4 * c) = cst[rr];
            }
        }
        if (ii < 6) stage((ii + 2) % 3, ii + 2);
        if (ii < 7) ld_a(na, ap0 + (ii + 1) * 64);

        const float* Wb = Wl[ii % 3];
        const short8 a0 = pack8(ra[0], ra[1]);
        const short8 a1 = pack8(ra[2], ra[3]);
        f32x4 acc[4];
        #pragma unroll
        for (int td = 0; td < 4; ++td) {
            const int r = 16 * td + c;
            const float4 f0 = *(const float4*)&Wb[(r * 16 + ((2 * q)     ^ c)) * 4];
            const float4 f1 = *(const float4*)&Wb[(r * 16 + ((2 * q + 1) ^ c)) * 4];
            const float4 f2 = *(const float4*)&Wb[(r * 16 + ((2 * q + 8) ^ c)) * 4];
            const float4 f3 = *(const float4*)&Wb[(r * 16 + ((2 * q + 9) ^ c)) * 4];
            const short8 b0 = pack8(f0, f1);
            const short8 b1 = pack8(f2, f3);
            f32x4 z = {0.f, 0.f, 0.f, 0.f};
            z = __builtin_amdgcn_mfma_f32_16x16x32_bf16(a0, b0, z, 0, 0, 0);
            z = __builtin_amdgcn_mfma_f32_16x16x32_bf16(a1, b1, z, 0, 0, 0);
            acc[td] = z;
        }
        // pack C row rr: d' = 4c..4c+3 <- acc[0..3][rr]
        #pragma unroll
        for (int rr = 0; rr < 4; ++rr) {
            cst[rr].x = (unsigned int)f2bf(acc[0][rr]) | ((unsigned int)f2bf(acc[1][rr]) << 16);
            cst[rr].y = (unsigned int)f2bf(acc[2][rr]) | ((unsigned int)f2bf(acc[3][rr]) << 16);
        }
        #pragma unroll
        for (int j = 0; j < 4; ++j) ra[j] = na[j];
    }
    #pragma unroll
    for (int rr = 0; rr < 4; ++rr) {         // last iteration's C
        const int bq = 16 * wv + 4 * q + rr;
        *(uint2*)(xh + (((size_t)o * NB + bq) * NI + (ig * 8 + 7)) * ND + 4 * c) = cst[rr];
    }
}

// Softmax stats per (b,i): m = max_o logits, 1/Z. 128 blocks.
__global__ __launch_bounds__(256) void k_soft(const float* __restrict__ b_in,
                                              float* __restrict__ mz) {
    const int p = blockIdx.x * 256 + threadIdx.x;        // p = b*512 + i
    const int b = p >> 9, i = p & 511;
    const float* bp = b_in + (size_t)b * NO * NI + i;
    float v[NO];
    #pragma unroll
    for (int oo = 0; oo < NO; ++oo) v[oo] = bp[(size_t)oo * NI];
    float m = v[0];
    #pragma unroll
    for (int oo = 1; oo < NO; ++oo) m = fmaxf(m, v[oo]);
    float Z = 0.f;
    #pragma unroll
    for (int oo = 0; oo < NO; ++oo) Z += __expf(v[oo] - m);
    mz[p] = m;
    mz[NB * NI + p] = 1.0f / Z;
}

// Routing step, block = (b,o). Hybrid tile: rows 0..255 DMA'd to LDS (32 KB),
// rows 256..511 in registers (8 uint4/thread, issued first so softmax covers
// their latency). Static LDS 35.3 KB -> 4 blocks/CU (was 2). All d-indexed data
// is in d'-space; only STEP==2's output write remaps d = 16*(t&3) + (t>>2).
template<int STEP>
__global__ __launch_bounds__(256) void k_route(const unsigned short* __restrict__ xh,
                                               const float* __restrict__ b_in,
                                               const float* __restrict__ mz,
                                               float* __restrict__ b_out,
                                               float* __restrict__ outp) {
    __shared__ unsigned short tile[256 * ND];  // 32 KB, rows 0..255
    __shared__ float c_s[NI];
    __shared__ float P[4 * 64];
    __shared__ float o_s[64];

    const int t  = threadIdx.x;
    const int b  = blockIdx.x >> 5;
    const int o  = blockIdx.x & 31;
    const int wv = t >> 6;
    const int l  = t & 63;
    const int dg = t & 7;
    const int ip = t >> 3;

    const unsigned short* gsrc = xh + ((size_t)o * NB + b) * NI * ND;

    // Register half first (latency overlapped by DMA issue + softmax).
    uint4 raw[8];
    #pragma unroll
    for (int k = 0; k < 8; ++k)
        raw[k] = *(const uint4*)(gsrc + (size_t)(256 + 32 * k + ip) * ND + dg * 8);

    // DMA half: wave wv covers 8 KB as 8 x 1-KB instrs (linear layout).
    #pragma unroll
    for (int k = 0; k < 8; ++k)
        GL2LDS(gsrc + wv * 4096 + k * 512 + l * 8, tile + wv * 4096 + k * 512);

    const float* bp = (STEP > 0) ? (b_in + ((size_t)b * NO + o) * NI) : nullptr;
    if (STEP > 0) {
        const float* mrow = mz + (size_t)b * NI;
        const float* zrow = mz + (size_t)(NB * NI) + (size_t)b * NI;
        #pragma unroll
        for (int s = 0; s < 2; ++s) {
            const int i = t + s * 256;
            c_s[i] = __expf(bp[i] - mrow[i]) * zrow[i];
        }
    }
    __syncthreads();                                     // DMA + c_s visible

    // c-weighted accumulation of s[d'] over both halves.
    float acc[8] = {0, 0, 0, 0, 0, 0, 0, 0};
    #pragma unroll
    for (int k = 0; k < 8; ++k) {                        // LDS half, rows 32k+ip
        const int i = 32 * k + ip;
        const uint4 rl = *(const uint4*)(tile + i * ND + dg * 8);
        const float cw = (STEP == 0) ? 0.03125f : c_s[i];
        acc[0] += cw * blo(rl.x); acc[1] += cw * bhi(rl.x);
        acc[2] += cw * blo(rl.y); acc[3] += cw * bhi(rl.y);
        acc[4] += cw * blo(rl.z); acc[5] += cw * bhi(rl.z);
        acc[6] += cw * blo(rl.w); acc[7] += cw * bhi(rl.w);
    }
    #pragma unroll
    for (int k = 0; k < 8; ++k) {                        // register half, rows 256+32k+ip
        const float cw = (STEP == 0) ? 0.03125f : c_s[256 + 32 * k + ip];
        acc[0] += cw * blo(raw[k].x); acc[1] += cw * bhi(raw[k].x);
        acc[2] += cw * blo(raw[k].y); acc[3] += cw * bhi(raw[k].y);
        acc[4] += cw * blo(raw[k].z); acc[5] += cw * bhi(raw[k].z);
        acc[6] += cw * blo(raw[k].w); acc[7] += cw * bhi(raw[k].w);
    }
    #pragma unroll
    for (int j = 0; j < 8; ++j) {          // reduce over ip within wave (bits 3..5)
        acc[j] += __shfl_xor(acc[j], 8);
        acc[j] += __shfl_xor(acc[j], 16);
        acc[j] += __shfl_xor(acc[j], 32);
    }
    if (l < 8) {
        #pragma unroll
        for (int j = 0; j < 8; ++j) P[wv * 64 + l * 8 + j] = acc[j];
    }
    __syncthreads();

    // Wave 0: finish s[d'], squash, emit out vector (o_s in d'-space).
    if (t < 64) {
        const float sv = P[t] + P[64 + t] + P[128 + t] + P[192 + t];
        float s2 = sv * sv;
        #pragma unroll
        for (int m = 1; m < 64; m <<= 1) s2 += __shfl_xor(s2, m);
        const float n = sqrtf(s2);
        const float sc = (s2 / (1.0f + s2)) / (n + 1e-8f);
        const float ov = sv * sc;
        o_s[t] = ov;
        if (STEP == 2) {
            const int d = 16 * (t & 3) + (t >> 2);       // d' -> d remap
            outp[((size_t)b * NO + o) * ND + d] = ov;
        }
    }
    __syncthreads();

    // b-update: dot per row (d'-space), reduce across dg (bits 0..2).
    if (STEP < 2) {
        float oc[8];
        #pragma unroll
        for (int j = 0; j < 8; ++j) oc[j] = o_s[dg * 8 + j];
        float w1 = 0.f, w2 = 0.f;
        #pragma unroll
        for (int k = 0; k < 8; ++k) {                    // LDS half
            const uint4 rl = *(const uint4*)(tile + (32 * k + ip) * ND + dg * 8);
            float pd = blo(rl.x) * oc[0] + bhi(rl.x) * oc[1]
                     + blo(rl.y) * oc[2] + bhi(rl.y) * oc[3]
                     + blo(rl.z) * oc[4] + bhi(rl.z) * oc[5]
                     + blo(rl.w) * oc[6] + bhi(rl.w) * oc[7];
            pd += __shfl_xor(pd, 1);
            pd += __shfl_xor(pd, 2);
            pd += __shfl_xor(pd, 4);
            if (k == dg) w1 = pd;
        }
        #pragma unroll
        for (int k = 0; k < 8; ++k) {                    // register half
            float pd = blo(raw[k].x) * oc[0] + bhi(raw[k].x) * oc[1]
                     + blo(raw[k].y) * oc[2] + bhi(raw[k].y) * oc[3]
                     + blo(raw[k].z) * oc[4] + bhi(raw[k].z) * oc[5]
                     + blo(raw[k].w) * oc[6] + bhi(raw[k].w) * oc[7];
            pd += __shfl_xor(pd, 1);
            pd += __shfl_xor(pd, 2);
            pd += __shfl_xor(pd, 4);
            if (k == dg) w2 = pd;
        }
        const int i1 = 32 * dg + ip;                     // row from LDS half
        const int i2 = 256 + 32 * dg + ip;               // row from register half
        float* bo = b_out + ((size_t)b * NO + o) * NI;
        bo[i1] = ((STEP == 0) ? 0.f : bp[i1]) + w1;
        bo[i2] = ((STEP == 0) ? 0.f : bp[i2]) + w2;
    }
}

extern "C" void kernel_launch(void* const* d_in, const int* in_sizes, int n_in,
                              void* d_out, int out_size, void* d_ws, size_t ws_size,
                              hipStream_t stream) {
    const float* x = (const float*)d_in[0];        // [64,512,64] fp32
    const float* w = (const float*)d_in[1];        // [32,512,64,64] fp32
    float* outp = (float*)d_out;                   // [64,32,64] fp32

    char* ws = (char*)d_ws;
    unsigned short* xh = (unsigned short*)ws;                       // 128 MiB bf16 xh[o][b][i][d']
    float* ba = (float*)(ws + (size_t)134217728);                   // 4 MiB logits A
    float* bb = (float*)(ws + (size_t)134217728 + 4194304);         // 4 MiB logits B
    float* mz = (float*)(ws + (size_t)134217728 + 2 * 4194304);     // 256 KiB m / 1/Z

    k_gemm<<<dim3(2048), dim3(256), 0, stream>>>(x, w, xh);
    k_route<0><<<dim3(2048), dim3(256), 0, stream>>>(xh, nullptr, nullptr, ba, nullptr);
    k_soft<<<dim3(128), dim3(256), 0, stream>>>(ba, mz);
    k_route<1><<<dim3(2048), dim3(256), 0, stream>>>(xh, ba, mz, bb, nullptr);
    k_soft<<<dim3(128), dim3(256), 0, stream>>>(bb, mz);
    k_route<2><<<dim3(2048), dim3(256), 0, stream>>>(xh, bb, mz, nullptr, outp);
}